// Round 1
// baseline (1505.290 us; speedup 1.0000x reference)
//
#include <hip/hip_runtime.h>
#include <math.h>

#define TDIM 36
#define PDIM 161        // 2*80+1 atoms
#define PPAD 164        // PDIM padded to /4 (float4 k-loop), stride 656B = 16B-aligned
#define TPAD 44         // TDIM padded; 44 breaks the stride-40 (==0 mod 32) bank collision
#define NCOL 50
#define NITER 100
#define PITER 400       // power-iteration steps; worst-case rel err <= 1/(2*K*e) ~ 4.6e-4

// ---------------- setup: build D, normalize, spectral norm via power iteration ---------

__device__ __forceinline__ float block_reduce_sum256(float v, float* red4, int tid) {
  #pragma unroll
  for (int off = 32; off > 0; off >>= 1) v += __shfl_down(v, off, 64);
  if ((tid & 63) == 0) red4[tid >> 6] = v;
  __syncthreads();
  float r = red4[0] + red4[1] + red4[2] + red4[3];
  __syncthreads();
  return r;
}

__global__ __launch_bounds__(256)
void setup_kernel(const float* __restrict__ rho, const float* __restrict__ theta,
                  float* __restrict__ wsD, float* __restrict__ wsS,
                  float* __restrict__ dic)
{
  __shared__ float Dl[TDIM][PDIM];
  __shared__ float v[PDIM];
  __shared__ float u[TDIM];
  __shared__ float up[TDIM][8];
  __shared__ float red4[4];
  const int tid = threadIdx.x;

  // build one dictionary column per thread
  if (tid < PDIM) {
    if (tid == 0) {
      for (int t = 0; t < TDIM; ++t) Dl[t][0] = 1.0f;
    } else {
      const bool is_sin = tid > 80;
      const int n = is_sin ? (tid - 81) : (tid - 1);
      const float rr = 0.001f + 1.149f / (1.0f + expf(-rho[n]));   // sigmoid squash
      const float th = 3.14159265358979f / (1.0f + expf(-theta[n]));
      const float lr = logf(rr);                                    // rr >= 0.001 > 0
      float s2 = 0.0f;
      for (int t = 0; t < TDIM; ++t) {
        const float ft = (float)t;
        const float pw = expf(ft * lr);                             // rr^t
        const float ang = ft * th;
        const float val = pw * (is_sin ? sinf(ang) : cosf(ang));
        Dl[t][tid] = val;
        s2 += val * val;
      }
      const float inv = 1.0f / sqrtf(s2);                           // column L2 normalize
      for (int t = 0; t < TDIM; ++t) Dl[t][tid] *= inv;
    }
  }
  __syncthreads();

  // write normalized D to workspace and to the `dic` output
  for (int i = tid; i < TDIM * PDIM; i += 256) {
    const int t = i / PDIM, p = i - t * PDIM;
    const float val = Dl[t][p];
    wsD[i] = val;
    dic[i] = val;
  }

  // power iteration on M = D^T D (apply as D then D^T); v0 = ones
  if (tid < PDIM) v[tid] = 1.0f;
  __syncthreads();

  for (int it = 0; it <= PITER; ++it) {
    // u = D v : 36 rows x 7 segments of 23
    if (tid < 252) {
      const int row = tid / 7, s = tid - row * 7;
      const int p0 = s * 23;
      float a = 0.0f;
      for (int p = p0; p < p0 + 23; ++p) a += Dl[row][p] * v[p];
      up[row][s] = a;
    }
    __syncthreads();
    if (tid < TDIM) {
      float a = 0.0f;
      #pragma unroll
      for (int s = 0; s < 7; ++s) a += up[tid][s];
      u[tid] = a;
    }
    __syncthreads();
    // w = D^T u
    float wv = 0.0f;
    if (tid < PDIM) {
      float a = 0.0f;
      for (int t = 0; t < TDIM; ++t) a += Dl[t][tid] * u[t];
      wv = a;
    }
    if (it == PITER) {
      // Rayleigh quotient lam = (v.Mv)/(v.v); v is normalized (last step did it&3==3)
      const float num = block_reduce_sum256((tid < PDIM) ? v[tid] * wv : 0.0f, red4, tid);
      const float den = block_reduce_sum256((tid < PDIM) ? v[tid] * v[tid] : 0.0f, red4, tid);
      if (tid == 0) {
        const float lam1 = num / den;
        const float li = 1.0f / lam1;       // L_inv = 1/||DtD||_2
        wsS[0] = li;
        wsS[1] = 0.1f * li;                 // thr = lam_f * L_inv
      }
    } else if ((it & 3) == 3) {
      // renormalize every 4 steps (lam^4 <= trace^4 ~ 1.5e9: no overflow)
      const float ss = block_reduce_sum256((tid < PDIM) ? wv * wv : 0.0f, red4, tid);
      const float sc = rsqrtf(ss);
      if (tid < PDIM) v[tid] = wv * sc;
      __syncthreads();
    } else {
      if (tid < PDIM) v[tid] = wv;
      __syncthreads();
    }
  }
}

// ---------------- main: per-batch FISTA, all state resident in LDS ---------------------
// x_new = shrink(y + L_inv * D^T (Y - D y), thr)   [== A y + B of the reference]

__device__ __forceinline__ float shrink_upd(float w, float thr, float ttf,
                                            float xold, float& ynew) {
  float a = fabsf(w) - thr;
  a = a > 0.0f ? a : 0.0f;
  const float xn = copysignf(a, w);
  ynew = (1.0f + ttf) * xn - ttf * xold;
  return xn;
}

__global__ __launch_bounds__(512, 2)
void fista_kernel(const float* __restrict__ xin, const float* __restrict__ wsD,
                  const float* __restrict__ wsS, float* __restrict__ outC,
                  float* __restrict__ outR)
{
  extern __shared__ float sm[];
  float* Ds = sm;                        // [TDIM][PPAD]  row-contiguous D (p fast)
  float* Dt = Ds + TDIM * PPAD;          // [PPAD][TPAD]  transposed D (t fast)
  float* Yc = Dt + PPAD * TPAD;          // [NCOL][TPAD]  input columns (t fast)
  float* Rs = Yc + NCOL * TPAD;          // [NCOL][TPAD]  residuals
  float* Xs = Rs + NCOL * TPAD;          // [NCOL][PPAD]  FISTA x
  float* Ys = Xs + NCOL * PPAD;          // [NCOL][PPAD]  FISTA y

  const int tid = threadIdx.x;
  const int b = blockIdx.x;
  const float L_inv = wsS[0];
  const float thr = wsS[1];

  // stage D into both layouts (zero the p-pad so padded k-loops are harmless)
  for (int i = tid; i < TDIM * PPAD; i += 512) {
    const int t = i / PPAD, p = i - t * PPAD;
    const float val = (p < PDIM) ? wsD[t * PDIM + p] : 0.0f;
    Ds[i] = val;
    Dt[p * TPAD + t] = val;
  }
  // stage this batch item's Y, transposed to [c][t]
  const float* xb = xin + b * TDIM * NCOL;
  for (int i = tid; i < TDIM * NCOL; i += 512) {
    const int t = i / NCOL, d = i - t * NCOL;
    Yc[d * TPAD + t] = xb[i];
  }
  // x0 = y0 = 0 (pads included -> they stay 0 forever)
  for (int i = tid; i < NCOL * PPAD; i += 512) { Xs[i] = 0.0f; Ys[i] = 0.0f; }
  __syncthreads();

  // step-1 tiles: 2t x 2c over 36x50 -> 18*25 = 450 active threads
  const int s1c = tid / 18;
  const int s1t = tid - s1c * 18;
  const bool act1 = tid < 450;
  // step-2 tiles: 4p x 5c over 164x50 -> 41*10 = 410 active threads
  const int s2c = tid % 10;
  const int s2p = tid / 10;
  const bool act2 = tid < 410;

  float tk = 1.0f;

  for (int it = 0; it < NITER; ++it) {
    // ---- step 1: Rs[c][t] = Yc[c][t] - sum_p Ds[t][p] * Ys[c][p]
    if (act1) {
      const int t0 = 2 * s1t, c0 = 2 * s1c;
      const float4* dr0 = (const float4*)(Ds + t0 * PPAD);
      const float4* dr1 = (const float4*)(Ds + (t0 + 1) * PPAD);
      const float4* yr0 = (const float4*)(Ys + c0 * PPAD);
      const float4* yr1 = (const float4*)(Ys + (c0 + 1) * PPAD);
      float a00 = 0.f, a01 = 0.f, a10 = 0.f, a11 = 0.f;
      #pragma unroll 4
      for (int k = 0; k < PPAD / 4; ++k) {
        const float4 d0 = dr0[k], d1 = dr1[k], y0 = yr0[k], y1 = yr1[k];
        a00 += d0.x * y0.x + d0.y * y0.y + d0.z * y0.z + d0.w * y0.w;
        a01 += d0.x * y1.x + d0.y * y1.y + d0.z * y1.z + d0.w * y1.w;
        a10 += d1.x * y0.x + d1.y * y0.y + d1.z * y0.z + d1.w * y0.w;
        a11 += d1.x * y1.x + d1.y * y1.y + d1.z * y1.z + d1.w * y1.w;
      }
      Rs[c0 * TPAD + t0]           = Yc[c0 * TPAD + t0]           - a00;
      Rs[(c0 + 1) * TPAD + t0]     = Yc[(c0 + 1) * TPAD + t0]     - a01;
      Rs[c0 * TPAD + t0 + 1]       = Yc[c0 * TPAD + t0 + 1]       - a10;
      Rs[(c0 + 1) * TPAD + t0 + 1] = Yc[(c0 + 1) * TPAD + t0 + 1] - a11;
    }
    __syncthreads();

    // FISTA momentum schedule (uniform across threads; `done` freeze can't trigger
    // at TOL=1e-5 over 2M elems, and continuing past it only reduces error)
    const float tnew = 0.5f * (1.0f + sqrtf(1.0f + 4.0f * tk * tk));
    const float ttf = (tk - 1.0f) / tnew;
    tk = tnew;

    // ---- step 2: w = y + L_inv * D^T r ; x,y update
    if (act2) {
      const int p0 = 4 * s2p, c0 = 5 * s2c;
      float acc[5][4];
      #pragma unroll
      for (int i = 0; i < 5; ++i)
        #pragma unroll
        for (int j = 0; j < 4; ++j) acc[i][j] = 0.0f;
      #pragma unroll
      for (int k = 0; k < TDIM / 4; ++k) {
        const float4 dv0 = *(const float4*)(Dt + (p0 + 0) * TPAD + 4 * k);
        const float4 dv1 = *(const float4*)(Dt + (p0 + 1) * TPAD + 4 * k);
        const float4 dv2 = *(const float4*)(Dt + (p0 + 2) * TPAD + 4 * k);
        const float4 dv3 = *(const float4*)(Dt + (p0 + 3) * TPAD + 4 * k);
        #pragma unroll
        for (int i = 0; i < 5; ++i) {
          const float4 rv = *(const float4*)(Rs + (c0 + i) * TPAD + 4 * k);
          acc[i][0] += dv0.x * rv.x + dv0.y * rv.y + dv0.z * rv.z + dv0.w * rv.w;
          acc[i][1] += dv1.x * rv.x + dv1.y * rv.y + dv1.z * rv.z + dv1.w * rv.w;
          acc[i][2] += dv2.x * rv.x + dv2.y * rv.y + dv2.z * rv.z + dv2.w * rv.w;
          acc[i][3] += dv3.x * rv.x + dv3.y * rv.y + dv3.z * rv.z + dv3.w * rv.w;
        }
      }
      #pragma unroll
      for (int i = 0; i < 5; ++i) {
        const int c = c0 + i;
        const float4 yv = *(const float4*)(Ys + c * PPAD + p0);
        const float4 xv = *(const float4*)(Xs + c * PPAD + p0);
        const float w0 = yv.x + L_inv * acc[i][0];
        const float w1 = yv.y + L_inv * acc[i][1];
        const float w2 = yv.z + L_inv * acc[i][2];
        const float w3 = yv.w + L_inv * acc[i][3];
        float yn0, yn1, yn2, yn3;
        const float x0 = shrink_upd(w0, thr, ttf, xv.x, yn0);
        const float x1 = shrink_upd(w1, thr, ttf, xv.y, yn1);
        const float x2 = shrink_upd(w2, thr, ttf, xv.z, yn2);
        const float x3 = shrink_upd(w3, thr, ttf, xv.w, yn3);
        *(float4*)(Xs + c * PPAD + p0) = make_float4(x0, x1, x2, x3);
        *(float4*)(Ys + c * PPAD + p0) = make_float4(yn0, yn1, yn2, yn3);
      }
    }
    __syncthreads();
  }

  // ---- outputs: C = x_fin (coalesced global writes)
  float* Cb = outC + b * PDIM * NCOL;
  for (int i = tid; i < PDIM * NCOL; i += 512) {
    const int p = i / NCOL, c = i - p * NCOL;
    Cb[i] = Xs[c * PPAD + p];
  }
  // reconst = D @ C, same tiling as step 1 but on Xs
  if (act1) {
    const int t0 = 2 * s1t, c0 = 2 * s1c;
    const float4* dr0 = (const float4*)(Ds + t0 * PPAD);
    const float4* dr1 = (const float4*)(Ds + (t0 + 1) * PPAD);
    const float4* xr0 = (const float4*)(Xs + c0 * PPAD);
    const float4* xr1 = (const float4*)(Xs + (c0 + 1) * PPAD);
    float a00 = 0.f, a01 = 0.f, a10 = 0.f, a11 = 0.f;
    #pragma unroll 4
    for (int k = 0; k < PPAD / 4; ++k) {
      const float4 d0 = dr0[k], d1 = dr1[k], y0 = xr0[k], y1 = xr1[k];
      a00 += d0.x * y0.x + d0.y * y0.y + d0.z * y0.z + d0.w * y0.w;
      a01 += d0.x * y1.x + d0.y * y1.y + d0.z * y1.z + d0.w * y1.w;
      a10 += d1.x * y0.x + d1.y * y0.y + d1.z * y0.z + d1.w * y0.w;
      a11 += d1.x * y1.x + d1.y * y1.y + d1.z * y1.z + d1.w * y1.w;
    }
    float* Rb = outR + b * TDIM * NCOL;
    Rb[t0 * NCOL + c0]           = a00;
    Rb[t0 * NCOL + c0 + 1]       = a01;
    Rb[(t0 + 1) * NCOL + c0]     = a10;
    Rb[(t0 + 1) * NCOL + c0 + 1] = a11;
  }
}

// ---------------- launch --------------------------------------------------------------

extern "C" void kernel_launch(void* const* d_in, const int* in_sizes, int n_in,
                              void* d_out, int out_size, void* d_ws, size_t ws_size,
                              hipStream_t stream) {
  const float* x     = (const float*)d_in[0];   // (256, 36, 50)
  const float* rho   = (const float*)d_in[1];   // (80,)
  const float* theta = (const float*)d_in[2];   // (80,)

  float* out    = (float*)d_out;
  float* outC   = out;                              // 256*161*50
  float* outDic = out + 256 * PDIM * NCOL;          // 36*161
  float* outR   = outDic + TDIM * PDIM;             // 256*36*50

  float* wsD = (float*)d_ws;                        // 36*161 normalized dictionary
  float* wsS = wsD + TDIM * PDIM;                   // [L_inv, thr]

  hipLaunchKernelGGL(setup_kernel, dim3(1), dim3(256), 0, stream,
                     rho, theta, wsD, wsS, outDic);

  const size_t smem = (size_t)(TDIM * PPAD + PPAD * TPAD + 2 * NCOL * TPAD
                               + 2 * NCOL * PPAD) * sizeof(float);  // 135,680 B
  hipLaunchKernelGGL(fista_kernel, dim3(256), dim3(512), smem, stream,
                     x, wsD, wsS, outC, outR);
}